// Round 9
// baseline (318.583 us; speedup 1.0000x reference)
//
#include <hip/hip_runtime.h>
#include <hip/hip_cooperative_groups.h>

namespace cg = cooperative_groups;

#define NN 50000
#define NPAD 50048           // 782 * 64 (featb rows, tail zeroed)
#define NE 500000
#define DD 128
#define NTILE 782            // ceil(NN/64)
#define OFFS_PAD 50176       // 49*1024, >= NN+1
#define COOP_BLOCKS 256
#define COOP_THREADS 1024
#define COOP_NT (COOP_BLOCKS * COOP_THREADS)   // 262144

// ALPHA = 0.5 → both sqrt(ALPHA) and sqrt(1-ALPHA) are sqrt(0.5).
__device__ __constant__ float SQ_A = 0.70710678118654752440f;

typedef __attribute__((ext_vector_type(8))) short short8;
typedef __attribute__((ext_vector_type(4))) float float4v;

// float → bf16 bits, round-to-nearest-even.
__device__ inline ushort f2bf(float f)
{
    uint u = __float_as_uint(f);
    u += 0x7fffu + ((u >> 16) & 1u);
    return (ushort)(u >> 16);
}
__device__ inline uint pk2(float a, float b)
{
    return (uint)f2bf(a) | ((uint)f2bf(b) << 16);
}
__device__ inline float bf_lo(uint d) { return __uint_as_float(d << 16); }
__device__ inline float bf_hi(uint d) { return __uint_as_float(d & 0xffff0000u); }

// ---------------------------------------------------------------------------
// Prep: feat fp32 → featb bf16 [NPAD][128] (rows >= NN zeroed);
//       W/loop_w → wtb bf16 [3][prow=128][k=128], scaled by sqrt(.5) and
//       ROW-PERMUTED so that B-frag row mq of tile nt holds actual column
//       col0 + 2*mq + nt → epilogue lanes own ADJACENT cols → packed stores.
//       prow(c) = (c>>5)*32 + (c&1)*16 + ((c&31)>>1).
// ---------------------------------------------------------------------------
#define PREP_FEAT (NPAD * 16)        // 16 chunks of 8 elems per row
#define PREP_WTB  (3 * 2048)         // per seg: 16 k-chunks * 128 cols
#define PREP_TASKS (PREP_FEAT + PREP_WTB)

__global__ __launch_bounds__(256)
void prep_kernel(const float* __restrict__ feat,
                 const float* __restrict__ weight,
                 const float* __restrict__ loop_w,
                 ushort* __restrict__ featb,
                 ushort* __restrict__ wtb)
{
    int t = blockIdx.x * 256 + threadIdx.x;
    if (t < PREP_FEAT) {
        int row = t >> 4;
        int c   = t & 15;            // k-chunk: elems c*8 .. c*8+7
        float4 v0 = make_float4(0.f, 0.f, 0.f, 0.f), v1 = v0;
        if (row < NN) {
            const float4* p = (const float4*)(feat + (size_t)row * DD + c * 8);
            v0 = p[0]; v1 = p[1];
        }
        uint4 pk;
        pk.x = pk2(v0.x, v0.y); pk.y = pk2(v0.z, v0.w);
        pk.z = pk2(v1.x, v1.y); pk.w = pk2(v1.z, v1.w);
        *(uint4*)&featb[(size_t)row * DD + c * 8] = pk;
    } else if (t < PREP_TASKS) {
        int u   = t - PREP_FEAT;
        int seg = u >> 11;           // 0,1 → relations; 2 → loop
        int c   = (u >> 7) & 15;     // k-chunk
        int col = u & 127;           // actual output column
        const float* wsrc = (seg < 2) ? (weight + (size_t)seg * DD * DD)
                                      : loop_w;
        float v[8];
#pragma unroll
        for (int j = 0; j < 8; ++j)
            v[j] = wsrc[(size_t)(c * 8 + j) * DD + col] * SQ_A;
        uint4 pk;
        pk.x = pk2(v[0], v[1]); pk.y = pk2(v[2], v[3]);
        pk.z = pk2(v[4], v[5]); pk.w = pk2(v[6], v[7]);
        int prow = (col >> 5) * 32 + ((col & 1) << 4) + ((col & 31) >> 1);
        *(uint4*)&wtb[((size_t)seg * DD + prow) * DD + c * 8] = pk;
    }
}

// ---------------------------------------------------------------------------
// Transform: ONE block per 64-node tile computes ALL THREE segs.
// A-frags (16×b128) loaded once from featb, reused across the 3 B-panels.
// wtb rows permuted (see prep) → lane mq owns adjacent cols 2mq,2mq+1 →
// epilogue: 16× packed-uint stores (hrelb) / 16× float2 stores (out).
//   seg 0/1 → hrelb[r] (bf16, sqrt(a) folded into wtb)
//   seg 2   → out = bias + loop message (fp32)
// ---------------------------------------------------------------------------
__global__ __launch_bounds__(256, 3)
void transform_mfma_kernel(const ushort* __restrict__ featb,
                           const ushort* __restrict__ wtb,
                           const float* __restrict__ h_bias,
                           ushort* __restrict__ hrelb,
                           float* __restrict__ out)
{
    const int tile  = blockIdx.x;
    const int node0 = tile * 64;
    const int wv    = threadIdx.x >> 6;
    const int lane  = threadIdx.x & 63;
    const int mq    = lane & 15;
    const int quad  = lane >> 4;
    const int col0  = wv * 32;

    // Load all A fragments once: A[m=mq][k=quad*8+j] per (mt, ks).
    short8 afrag[4][4];
#pragma unroll
    for (int mt = 0; mt < 4; ++mt) {
        const ushort* arow = featb + (size_t)(node0 + mt * 16 + mq) * DD;
#pragma unroll
        for (int ks = 0; ks < 4; ++ks)
            afrag[mt][ks] = *(const short8*)&arow[ks * 32 + quad * 8];
    }

#pragma unroll 1
    for (int seg = 0; seg < 3; ++seg) {
        const ushort* wseg = wtb + (size_t)seg * DD * DD;

        short8 bfrag[2][4];
#pragma unroll
        for (int nt = 0; nt < 2; ++nt)
#pragma unroll
            for (int ks = 0; ks < 4; ++ks)
                bfrag[nt][ks] = *(const short8*)
                    &wseg[(size_t)(col0 + nt * 16 + mq) * DD + ks * 32 + quad * 8];

        float4v acc[4][2];
#pragma unroll
        for (int mt = 0; mt < 4; ++mt)
#pragma unroll
            for (int nt = 0; nt < 2; ++nt)
                acc[mt][nt] = (float4v){0.f, 0.f, 0.f, 0.f};

#pragma unroll
        for (int mt = 0; mt < 4; ++mt)
#pragma unroll
            for (int ks = 0; ks < 4; ++ks)
#pragma unroll
                for (int nt = 0; nt < 2; ++nt)
                    acc[mt][nt] = __builtin_amdgcn_mfma_f32_16x16x32_bf16(
                        afrag[mt][ks], bfrag[nt][ks], acc[mt][nt], 0, 0, 0);

        // Epilogue. D: row = quad*4 + r; lane mq owns cols col0+2mq, +1.
        if (seg < 2) {
            ushort* hb = hrelb + (size_t)seg * NN * DD;
#pragma unroll
            for (int mt = 0; mt < 4; ++mt) {
#pragma unroll
                for (int r = 0; r < 4; ++r) {
                    int node = node0 + mt * 16 + quad * 4 + r;
                    if (node < NN) {
                        uint pk = pk2(acc[mt][0][r], acc[mt][1][r]);
                        *(uint*)&hb[(size_t)node * DD + col0 + 2 * mq] = pk;
                    }
                }
            }
        } else {
            float2 bv = *(const float2*)&h_bias[col0 + 2 * mq];
#pragma unroll
            for (int mt = 0; mt < 4; ++mt) {
#pragma unroll
                for (int r = 0; r < 4; ++r) {
                    int node = node0 + mt * 16 + quad * 4 + r;
                    if (node < NN) {
                        float2 v = make_float2(acc[mt][0][r] + bv.x,
                                               acc[mt][1][r] + bv.y);
                        *(float2*)&out[(size_t)node * DD + col0 + 2 * mq] = v;
                    }
                }
            }
        }
    }
}

// ---------------------------------------------------------------------------
// Cooperative CSR build: one kernel, 256 blocks × 1024 threads.
//   phase 0: zero offs           (one shot, COOP_NT > OFFS_PAD)
//   phase 1: histogram of dst    (grid-stride, 2 iters)
//   phase 2a: blocks 0..48 compute 1024-chunk sums → csum
//   phase 2b: blocks 0..48 apply exclusive scan → offs, cursor
//   phase 3: place payload[p] = ety*NN+src at cursor[dst]++
// ---------------------------------------------------------------------------
__global__ __launch_bounds__(COOP_THREADS)
void csr_coop_kernel(const int* __restrict__ src, const int* __restrict__ dst,
                     const int* __restrict__ ety,
                     int* __restrict__ offs, int* __restrict__ cursor,
                     int* __restrict__ csum, int* __restrict__ payload)
{
    cg::grid_group grid = cg::this_grid();
    const int tid  = blockIdx.x * COOP_THREADS + threadIdx.x;
    const int lane = threadIdx.x & 63;
    const int wvi  = threadIdx.x >> 6;
    __shared__ int ws[16];

    // phase 0: zero offs
    if (tid < OFFS_PAD) offs[tid] = 0;
    grid.sync();

    // phase 1: histogram
    for (int e = tid; e < NE; e += COOP_NT)
        atomicAdd(&offs[dst[e]], 1);
    grid.sync();

    // phase 2a: per-chunk sums (blocks 0..48)
    if (blockIdx.x < 49) {
        int i = blockIdx.x * 1024 + threadIdx.x;
        int v = offs[i];
        for (int d = 32; d > 0; d >>= 1) v += __shfl_down(v, d, 64);
        if (lane == 0) ws[wvi] = v;
        __syncthreads();
        if (threadIdx.x < 16) {
            int s = ws[threadIdx.x];
            for (int d = 8; d > 0; d >>= 1) s += __shfl_down(s, d, 64);
            if (threadIdx.x == 0) csum[blockIdx.x] = s;
        }
        __syncthreads();   // ws reused in 2b
    }
    grid.sync();

    // phase 2b: exclusive scan apply (blocks 0..48)
    if (blockIdx.x < 49) {
        int base = 0;
        for (int b = 0; b < 49; ++b)
            if (b < (int)blockIdx.x) base += csum[b];
        int i = blockIdx.x * 1024 + threadIdx.x;
        int v = offs[i];
        int inc = v;
#pragma unroll
        for (int d = 1; d < 64; d <<= 1) {
            int t = __shfl_up(inc, d, 64);
            if (lane >= d) inc += t;
        }
        if (lane == 63) ws[wvi] = inc;
        __syncthreads();
        int wbase = 0;
#pragma unroll
        for (int w = 0; w < 16; ++w)
            if (w < wvi) wbase += ws[w];
        int excl = base + wbase + inc - v;
        offs[i] = excl;                    // i == NN gets total (=NE) ✓
        if (i < NN) cursor[i] = excl;
    }
    grid.sync();

    // phase 3: place
    for (int e = tid; e < NE; e += COOP_NT) {
        int p = atomicAdd(&cursor[dst[e]], 1);
        payload[p] = ety[e] * NN + src[e];
    }
}

// ---------------------------------------------------------------------------
// Gather: one wave per node; bf16 messages, fp32 accumulate, 8 loads in
// flight. acc starts at out[n] (= bias + loop message).
// ---------------------------------------------------------------------------
__global__ __launch_bounds__(256)
void gather_kernel(const int* __restrict__ offs, const int* __restrict__ payload,
                   const ushort* __restrict__ hrelb, float* __restrict__ out)
{
    const int n = blockIdx.x * 4 + (threadIdx.x >> 6);
    if (n >= NN) return;
    const int lane = threadIdx.x & 63;
    const int e0 = offs[n];
    const int e1 = offs[n + 1];
    float* orow = out + (size_t)n * DD;
    float2 a0 = ((float2*)orow)[lane];
    float2 a1 = make_float2(0.f, 0.f);
    float2 a2 = make_float2(0.f, 0.f);
    float2 a3 = make_float2(0.f, 0.f);
    int e = e0;
    for (; e + 8 <= e1; e += 8) {
        uint d0 = *(const uint*)&hrelb[(size_t)payload[e]     * DD + lane * 2];
        uint d1 = *(const uint*)&hrelb[(size_t)payload[e + 1] * DD + lane * 2];
        uint d2 = *(const uint*)&hrelb[(size_t)payload[e + 2] * DD + lane * 2];
        uint d3 = *(const uint*)&hrelb[(size_t)payload[e + 3] * DD + lane * 2];
        uint d4 = *(const uint*)&hrelb[(size_t)payload[e + 4] * DD + lane * 2];
        uint d5 = *(const uint*)&hrelb[(size_t)payload[e + 5] * DD + lane * 2];
        uint d6 = *(const uint*)&hrelb[(size_t)payload[e + 6] * DD + lane * 2];
        uint d7 = *(const uint*)&hrelb[(size_t)payload[e + 7] * DD + lane * 2];
        a0.x += bf_lo(d0); a0.y += bf_hi(d0);
        a1.x += bf_lo(d1); a1.y += bf_hi(d1);
        a2.x += bf_lo(d2); a2.y += bf_hi(d2);
        a3.x += bf_lo(d3); a3.y += bf_hi(d3);
        a0.x += bf_lo(d4); a0.y += bf_hi(d4);
        a1.x += bf_lo(d5); a1.y += bf_hi(d5);
        a2.x += bf_lo(d6); a2.y += bf_hi(d6);
        a3.x += bf_lo(d7); a3.y += bf_hi(d7);
    }
    if (e + 4 <= e1) {
        uint d0 = *(const uint*)&hrelb[(size_t)payload[e]     * DD + lane * 2];
        uint d1 = *(const uint*)&hrelb[(size_t)payload[e + 1] * DD + lane * 2];
        uint d2 = *(const uint*)&hrelb[(size_t)payload[e + 2] * DD + lane * 2];
        uint d3 = *(const uint*)&hrelb[(size_t)payload[e + 3] * DD + lane * 2];
        a0.x += bf_lo(d0); a0.y += bf_hi(d0);
        a1.x += bf_lo(d1); a1.y += bf_hi(d1);
        a2.x += bf_lo(d2); a2.y += bf_hi(d2);
        a3.x += bf_lo(d3); a3.y += bf_hi(d3);
        e += 4;
    }
    for (; e < e1; ++e) {
        uint d0 = *(const uint*)&hrelb[(size_t)payload[e] * DD + lane * 2];
        a0.x += bf_lo(d0); a0.y += bf_hi(d0);
    }
    a0.x += a1.x + a2.x + a3.x;
    a0.y += a1.y + a2.y + a3.y;
    ((float2*)orow)[lane] = a0;
}

// ---------------------------------------------------------------------------
// Tier-2 fallback: atomic scatter from bf16 hrelb (needs offs zeroing? no —
// scatter path doesn't use offs at all).
// ---------------------------------------------------------------------------
__global__ __launch_bounds__(256)
void scatter_kernel(const int* __restrict__ src, const int* __restrict__ dst,
                    const int* __restrict__ ety,
                    const ushort* __restrict__ hrelb,
                    float* __restrict__ out)
{
    const int e = blockIdx.x * 4 + (threadIdx.x >> 6);
    if (e >= NE) return;
    const int lane = threadIdx.x & 63;
    uint d0 = *(const uint*)&hrelb[
        ((size_t)ety[e] * NN + src[e]) * DD + lane * 2];
    float* o = out + (size_t)dst[e] * DD + lane * 2;
    atomicAdd(o,     bf_lo(d0));
    atomicAdd(o + 1, bf_hi(d0));
}

// Tier-3 fallback: fp32 out-init (loop message + bias) + fused per-edge matvec.
__global__ __launch_bounds__(256)
void loop_init_kernel(const float* __restrict__ feat,
                      const float* __restrict__ loop_weight,
                      const float* __restrict__ h_bias,
                      float* __restrict__ out)
{
    const int n = blockIdx.x * 4 + (threadIdx.x >> 6);
    if (n >= NN) return;
    const int lane = threadIdx.x & 63;
    const float2 fv = ((const float2*)(feat + (size_t)n * DD))[lane];
    float a0 = h_bias[lane], a1 = h_bias[lane + 64];
    for (int k = 0; k < 64; ++k) {
        float f0 = __shfl(fv.x, k, 64);
        float f1 = __shfl(fv.y, k, 64);
        a0 += SQ_A * (f0 * loop_weight[(size_t)(2 * k) * DD + lane]
                    + f1 * loop_weight[(size_t)(2 * k + 1) * DD + lane]);
        a1 += SQ_A * (f0 * loop_weight[(size_t)(2 * k) * DD + lane + 64]
                    + f1 * loop_weight[(size_t)(2 * k + 1) * DD + lane + 64]);
    }
    out[(size_t)n * DD + lane] = a0;
    out[(size_t)n * DD + lane + 64] = a1;
}

__global__ __launch_bounds__(256)
void fused_edge_kernel(const float* __restrict__ feat,
                       const int* __restrict__ src, const int* __restrict__ dst,
                       const int* __restrict__ ety,
                       const float* __restrict__ weight,
                       float* __restrict__ out)
{
    const int wave  = threadIdx.x >> 6;
    const int lane  = threadIdx.x & 63;
    const int nwav  = gridDim.x * 4;
    for (int e = blockIdx.x * 4 + wave; e < NE; e += nwav) {
        const int s = src[e];
        const int d = dst[e];
        const int r = ety[e];
        const float2 fv = ((const float2*)(feat + (size_t)s * DD))[lane];
        const float* W = weight + (size_t)r * DD * DD;
        float a0 = 0.f, a1 = 0.f;
        for (int k = 0; k < 64; ++k) {
            float f0 = __shfl(fv.x, k, 64);
            float f1 = __shfl(fv.y, k, 64);
            a0 += f0 * W[(size_t)(2 * k) * DD + lane]
                + f1 * W[(size_t)(2 * k + 1) * DD + lane];
            a1 += f0 * W[(size_t)(2 * k) * DD + lane + 64]
                + f1 * W[(size_t)(2 * k + 1) * DD + lane + 64];
        }
        atomicAdd(out + (size_t)d * DD + lane,      SQ_A * a0);
        atomicAdd(out + (size_t)d * DD + lane + 64, SQ_A * a1);
    }
}

extern "C" void kernel_launch(void* const* d_in, const int* in_sizes, int n_in,
                              void* d_out, int out_size, void* d_ws, size_t ws_size,
                              hipStream_t stream)
{
    const float* feat   = (const float*)d_in[0];
    const int*   src    = (const int*)d_in[1];
    const int*   dst    = (const int*)d_in[2];
    const int*   ety    = (const int*)d_in[3];
    const float* weight = (const float*)d_in[4];
    const float* loop_w = (const float*)d_in[5];
    const float* h_bias = (const float*)d_in[6];
    float* out  = (float*)d_out;

    // Workspace layout (all sections 16B-multiple sized).
    char* p = (char*)d_ws;
    ushort* featb = (ushort*)p;  p += (size_t)NPAD * DD * 2;    // 12.81 MB
    ushort* wtb   = (ushort*)p;  p += (size_t)3 * DD * DD * 2;  // 96 KB
    ushort* hrelb = (ushort*)p;  p += (size_t)2 * NN * DD * 2;  // 25.6 MB
    const size_t need_t2 = (size_t)(p - (char*)d_ws);
    int* offs     = (int*)p;     p += (size_t)OFFS_PAD * 4;
    int* cursor   = (int*)p;     p += (size_t)OFFS_PAD * 4;
    int* csum     = (int*)p;     p += 64 * 4;
    int* payload  = (int*)p;     p += (size_t)NE * 4;
    const size_t need_full = (size_t)(p - (char*)d_ws);         // ~41.2 MB

    if (ws_size >= need_full) {
        prep_kernel<<<(PREP_TASKS + 255) / 256, 256, 0, stream>>>(
            feat, weight, loop_w, featb, wtb);
        transform_mfma_kernel<<<NTILE, 256, 0, stream>>>(
            featb, wtb, h_bias, hrelb, out);
        {
            void* args[] = {(void*)&src, (void*)&dst, (void*)&ety,
                            (void*)&offs, (void*)&cursor, (void*)&csum,
                            (void*)&payload};
            hipLaunchCooperativeKernel((const void*)csr_coop_kernel,
                                       dim3(COOP_BLOCKS), dim3(COOP_THREADS),
                                       args, 0, stream);
        }
        gather_kernel<<<(NN + 3) / 4, 256, 0, stream>>>(
            offs, payload, hrelb, out);
    } else if (ws_size >= need_t2) {
        prep_kernel<<<(PREP_TASKS + 255) / 256, 256, 0, stream>>>(
            feat, weight, loop_w, featb, wtb);
        transform_mfma_kernel<<<NTILE, 256, 0, stream>>>(
            featb, wtb, h_bias, hrelb, out);
        scatter_kernel<<<dim3((NE + 3) / 4), 256, 0, stream>>>(
            src, dst, ety, hrelb, out);
    } else {
        loop_init_kernel<<<(NN + 3) / 4, 256, 0, stream>>>(
            feat, loop_w, h_bias, out);
        fused_edge_kernel<<<dim3(2048), 256, 0, stream>>>(
            feat, src, dst, ety, weight, out);
    }
}

// Round 10
// 229.250 us; speedup vs baseline: 1.3897x; 1.3897x over previous
//
#include <hip/hip_runtime.h>

#define NN 50000
#define NPAD 50048           // 782 * 64 (featb rows, tail zeroed)
#define NE 500000
#define DD 128
#define NTILE 782            // ceil(NN/64)
#define OFFS_PAD 50176       // 49*1024, >= NN+1

// ALPHA = 0.5 → both sqrt(ALPHA) and sqrt(1-ALPHA) are sqrt(0.5).
__device__ __constant__ float SQ_A = 0.70710678118654752440f;

typedef __attribute__((ext_vector_type(8))) short short8;
typedef __attribute__((ext_vector_type(4))) float float4v;

// float → bf16 bits, round-to-nearest-even.
__device__ inline ushort f2bf(float f)
{
    uint u = __float_as_uint(f);
    u += 0x7fffu + ((u >> 16) & 1u);
    return (ushort)(u >> 16);
}
__device__ inline uint pk2(float a, float b)
{
    return (uint)f2bf(a) | ((uint)f2bf(b) << 16);
}
__device__ inline float bf_lo(uint d) { return __uint_as_float(d << 16); }
__device__ inline float bf_hi(uint d) { return __uint_as_float(d & 0xffff0000u); }

// ---------------------------------------------------------------------------
// Prep: feat fp32 → featb bf16 [NPAD][128] (rows >= NN zeroed);
//       W/loop_w → wtb bf16 [3][prow=128][k=128], scaled by sqrt(.5) and
//       ROW-PERMUTED so that B-frag row mq of tile nt holds actual column
//       col0 + 2*mq + nt → epilogue lanes own ADJACENT cols → packed stores.
//       prow(c) = (c>>5)*32 + (c&1)*16 + ((c&31)>>1).
//       zero offs[OFFS_PAD].
// ---------------------------------------------------------------------------
#define PREP_FEAT (NPAD * 16)        // 16 chunks of 8 elems per row
#define PREP_WTB  (3 * 2048)         // per seg: 16 k-chunks * 128 cols
#define PREP_ZERO (OFFS_PAD / 4)
#define PREP_TASKS (PREP_FEAT + PREP_WTB + PREP_ZERO)

__global__ __launch_bounds__(256)
void prep_kernel(const float* __restrict__ feat,
                 const float* __restrict__ weight,
                 const float* __restrict__ loop_w,
                 ushort* __restrict__ featb,
                 ushort* __restrict__ wtb,
                 int* __restrict__ offs)
{
    int t = blockIdx.x * 256 + threadIdx.x;
    if (t < PREP_FEAT) {
        int row = t >> 4;
        int c   = t & 15;            // k-chunk: elems c*8 .. c*8+7
        float4 v0 = make_float4(0.f, 0.f, 0.f, 0.f), v1 = v0;
        if (row < NN) {
            const float4* p = (const float4*)(feat + (size_t)row * DD + c * 8);
            v0 = p[0]; v1 = p[1];
        }
        uint4 pk;
        pk.x = pk2(v0.x, v0.y); pk.y = pk2(v0.z, v0.w);
        pk.z = pk2(v1.x, v1.y); pk.w = pk2(v1.z, v1.w);
        *(uint4*)&featb[(size_t)row * DD + c * 8] = pk;
    } else if (t < PREP_FEAT + PREP_WTB) {
        int u   = t - PREP_FEAT;
        int seg = u >> 11;           // 0,1 → relations; 2 → loop
        int c   = (u >> 7) & 15;     // k-chunk
        int col = u & 127;           // actual output column
        const float* wsrc = (seg < 2) ? (weight + (size_t)seg * DD * DD)
                                      : loop_w;
        float v[8];
#pragma unroll
        for (int j = 0; j < 8; ++j)
            v[j] = wsrc[(size_t)(c * 8 + j) * DD + col] * SQ_A;
        uint4 pk;
        pk.x = pk2(v[0], v[1]); pk.y = pk2(v[2], v[3]);
        pk.z = pk2(v[4], v[5]); pk.w = pk2(v[6], v[7]);
        int prow = (col >> 5) * 32 + ((col & 1) << 4) + ((col & 31) >> 1);
        *(uint4*)&wtb[((size_t)seg * DD + prow) * DD + c * 8] = pk;
    } else if (t < PREP_TASKS) {
        int u = t - (PREP_FEAT + PREP_WTB);
        ((int4*)offs)[u] = make_int4(0, 0, 0, 0);
    }
}

// ---------------------------------------------------------------------------
// Histogram.
// ---------------------------------------------------------------------------
__global__ __launch_bounds__(256)
void hist_kernel(const int* __restrict__ dst, int* __restrict__ offs)
{
    int e = blockIdx.x * 256 + threadIdx.x;
    if (e < NE) atomicAdd(&offs[dst[e]], 1);
}

// ---------------------------------------------------------------------------
// Parallel scan, two kernels over 49×1024 = OFFS_PAD elements (R8-proven).
// ---------------------------------------------------------------------------
__global__ __launch_bounds__(1024)
void scan_a_kernel(const int* __restrict__ offs, int* __restrict__ csum)
{
    __shared__ int ws[16];
    int i = blockIdx.x * 1024 + threadIdx.x;
    int v = offs[i];                       // padded region is zeroed
    for (int d = 32; d > 0; d >>= 1) v += __shfl_down(v, d, 64);
    int lane = threadIdx.x & 63, wv = threadIdx.x >> 6;
    if (lane == 0) ws[wv] = v;
    __syncthreads();
    if (threadIdx.x < 16) {
        int s = ws[threadIdx.x];
        for (int d = 8; d > 0; d >>= 1) s += __shfl_down(s, d, 64);
        if (threadIdx.x == 0) csum[blockIdx.x] = s;
    }
}

__global__ __launch_bounds__(1024)
void scan_apply_kernel(int* __restrict__ offs, int* __restrict__ cursor,
                       const int* __restrict__ csum)
{
    __shared__ int ws[16];
    const int bid  = blockIdx.x;
    const int lane = threadIdx.x & 63;
    const int wvi  = threadIdx.x >> 6;

    int base = 0;
    for (int b = 0; b < 49; ++b)
        if (b < bid) base += csum[b];

    int i = bid * 1024 + threadIdx.x;
    int v = offs[i];
    int inc = v;
#pragma unroll
    for (int d = 1; d < 64; d <<= 1) {
        int t = __shfl_up(inc, d, 64);
        if (lane >= d) inc += t;
    }
    if (lane == 63) ws[wvi] = inc;
    __syncthreads();
    int wbase = 0;
#pragma unroll
    for (int w = 0; w < 16; ++w) {
        int s = ws[w];
        if (w < wvi) wbase += s;
    }
    int excl = base + wbase + inc - v;
    offs[i] = excl;                        // i == NN gets total (=NE) ✓
    if (i < NN) cursor[i] = excl;
}

// payload[p] = (ety<<16) | src  (src < 65536 ✓).
__global__ __launch_bounds__(256)
void place_kernel(const int* __restrict__ src, const int* __restrict__ dst,
                  const int* __restrict__ ety,
                  int* __restrict__ cursor, int* __restrict__ payload)
{
    int e = blockIdx.x * 256 + threadIdx.x;
    if (e >= NE) return;
    int p = atomicAdd(&cursor[dst[e]], 1);
    payload[p] = (ety[e] << 16) | src[e];
}

// ---------------------------------------------------------------------------
// Fused aggregate + transform. One block per 64-node tile.
// Math: out[n] = bias + featb[n]@LWb + agg0[n]@W0b + agg1[n]@W1b
//   where agg_r[n] = Σ_{e: dst=n, ety=r} featb[src_e]  (fp32 acc → bf16).
// Phase 1 (gather): wave wv aggregates nodes [wv*16, wv*16+16); lane l owns
//   cols 2l,2l+1. Stores to sAgg[2][64][136] (stride 136 → even bank spread).
// Phase 2 (MFMA): shared fp32 acc over 3 B-panels; A from featb (global,
//   preloaded before gather) / sAgg (LDS). Epilogue: 16 float2 stores (out).
// ---------------------------------------------------------------------------
__global__ __launch_bounds__(256, 3)
void fused_agg_mfma_kernel(const ushort* __restrict__ featb,
                           const ushort* __restrict__ wtb,
                           const float* __restrict__ h_bias,
                           const int* __restrict__ offs,
                           const int* __restrict__ payload,
                           float* __restrict__ out)
{
    __shared__ ushort sAgg[2][64][136];   // 34.8 KB

    const int tile  = blockIdx.x;
    const int node0 = tile * 64;
    const int wv    = threadIdx.x >> 6;
    const int lane  = threadIdx.x & 63;
    const int mq    = lane & 15;
    const int quad  = lane >> 4;
    const int col0  = wv * 32;

    // Preload featb A-frags (independent of gather; hides behind it).
    short8 afrag[4][4];
#pragma unroll
    for (int mt = 0; mt < 4; ++mt) {
        const ushort* arow = featb + (size_t)(node0 + mt * 16 + mq) * DD;
#pragma unroll
        for (int ks = 0; ks < 4; ++ks)
            afrag[mt][ks] = *(const short8*)&arow[ks * 32 + quad * 8];
    }

    // --- Phase 1: gather-aggregate 16 nodes per wave. ---
#pragma unroll 1
    for (int i = 0; i < 16; ++i) {
        const int nl = wv * 16 + i;
        const int n  = node0 + nl;
        float2 a0 = make_float2(0.f, 0.f), b0 = a0;
        float2 a1 = make_float2(0.f, 0.f), b1 = a1;
        if (n < NN) {
            const int e0 = offs[n];
            const int e1 = offs[n + 1];
            int e = e0;
            for (; e + 2 <= e1; e += 2) {
                int p0 = payload[e], p1 = payload[e + 1];
                uint d0 = *(const uint*)&featb[(size_t)(p0 & 0xffff) * DD + lane * 2];
                uint d1 = *(const uint*)&featb[(size_t)(p1 & 0xffff) * DD + lane * 2];
                bool r0 = (p0 >> 16) != 0, r1 = (p1 >> 16) != 0;
                float lx0 = bf_lo(d0), ly0 = bf_hi(d0);
                float lx1 = bf_lo(d1), ly1 = bf_hi(d1);
                a0.x += r0 ? 0.f : lx0;  a0.y += r0 ? 0.f : ly0;
                a1.x += r0 ? lx0 : 0.f;  a1.y += r0 ? ly0 : 0.f;
                b0.x += r1 ? 0.f : lx1;  b0.y += r1 ? 0.f : ly1;
                b1.x += r1 ? lx1 : 0.f;  b1.y += r1 ? ly1 : 0.f;
            }
            if (e < e1) {
                int p0 = payload[e];
                uint d0 = *(const uint*)&featb[(size_t)(p0 & 0xffff) * DD + lane * 2];
                bool r0 = (p0 >> 16) != 0;
                float lx0 = bf_lo(d0), ly0 = bf_hi(d0);
                a0.x += r0 ? 0.f : lx0;  a0.y += r0 ? 0.f : ly0;
                a1.x += r0 ? lx0 : 0.f;  a1.y += r0 ? ly0 : 0.f;
            }
        }
        *(uint*)&sAgg[0][nl][2 * lane] = pk2(a0.x + b0.x, a0.y + b0.y);
        *(uint*)&sAgg[1][nl][2 * lane] = pk2(a1.x + b1.x, a1.y + b1.y);
    }
    __syncthreads();

    // --- Phase 2: MFMA, shared accumulator across 3 panels. ---
    float4v acc[4][2];
#pragma unroll
    for (int mt = 0; mt < 4; ++mt)
#pragma unroll
        for (int nt = 0; nt < 2; ++nt)
            acc[mt][nt] = (float4v){0.f, 0.f, 0.f, 0.f};

    // Panel: featb @ LWb (wtb seg 2).
    {
        const ushort* wseg = wtb + (size_t)2 * DD * DD;
        short8 bfrag[2][4];
#pragma unroll
        for (int nt = 0; nt < 2; ++nt)
#pragma unroll
            for (int ks = 0; ks < 4; ++ks)
                bfrag[nt][ks] = *(const short8*)
                    &wseg[(size_t)(col0 + nt * 16 + mq) * DD + ks * 32 + quad * 8];
#pragma unroll
        for (int mt = 0; mt < 4; ++mt)
#pragma unroll
            for (int ks = 0; ks < 4; ++ks)
#pragma unroll
                for (int nt = 0; nt < 2; ++nt)
                    acc[mt][nt] = __builtin_amdgcn_mfma_f32_16x16x32_bf16(
                        afrag[mt][ks], bfrag[nt][ks], acc[mt][nt], 0, 0, 0);
    }

    // Panels: sAgg[r] @ W_r b (wtb segs 0,1).
#pragma unroll 1
    for (int r = 0; r < 2; ++r) {
        const ushort* wseg = wtb + (size_t)r * DD * DD;
        short8 bfrag[2][4];
#pragma unroll
        for (int nt = 0; nt < 2; ++nt)
#pragma unroll
            for (int ks = 0; ks < 4; ++ks)
                bfrag[nt][ks] = *(const short8*)
                    &wseg[(size_t)(col0 + nt * 16 + mq) * DD + ks * 32 + quad * 8];
#pragma unroll
        for (int mt = 0; mt < 4; ++mt)
#pragma unroll
            for (int ks = 0; ks < 4; ++ks) {
                short8 a = *(const short8*)&sAgg[r][mt * 16 + mq][ks * 32 + quad * 8];
#pragma unroll
                for (int nt = 0; nt < 2; ++nt)
                    acc[mt][nt] = __builtin_amdgcn_mfma_f32_16x16x32_bf16(
                        a, bfrag[nt][ks], acc[mt][nt], 0, 0, 0);
            }
    }

    // Epilogue. D row = quad*4 + rr; lane mq owns cols col0+2mq, +1.
    float2 bv = *(const float2*)&h_bias[col0 + 2 * mq];
#pragma unroll
    for (int mt = 0; mt < 4; ++mt) {
#pragma unroll
        for (int rr = 0; rr < 4; ++rr) {
            int node = node0 + mt * 16 + quad * 4 + rr;
            if (node < NN) {
                float2 v = make_float2(acc[mt][0][rr] + bv.x,
                                       acc[mt][1][rr] + bv.y);
                *(float2*)&out[(size_t)node * DD + col0 + 2 * mq] = v;
            }
        }
    }
}

// ---------------------------------------------------------------------------
// Fallback (small ws): fp32 out-init + fused per-edge matvec.
// ---------------------------------------------------------------------------
__global__ __launch_bounds__(256)
void loop_init_kernel(const float* __restrict__ feat,
                      const float* __restrict__ loop_weight,
                      const float* __restrict__ h_bias,
                      float* __restrict__ out)
{
    const int n = blockIdx.x * 4 + (threadIdx.x >> 6);
    if (n >= NN) return;
    const int lane = threadIdx.x & 63;
    const float2 fv = ((const float2*)(feat + (size_t)n * DD))[lane];
    float a0 = h_bias[lane], a1 = h_bias[lane + 64];
    for (int k = 0; k < 64; ++k) {
        float f0 = __shfl(fv.x, k, 64);
        float f1 = __shfl(fv.y, k, 64);
        a0 += SQ_A * (f0 * loop_weight[(size_t)(2 * k) * DD + lane]
                    + f1 * loop_weight[(size_t)(2 * k + 1) * DD + lane]);
        a1 += SQ_A * (f0 * loop_weight[(size_t)(2 * k) * DD + lane + 64]
                    + f1 * loop_weight[(size_t)(2 * k + 1) * DD + lane + 64]);
    }
    out[(size_t)n * DD + lane] = a0;
    out[(size_t)n * DD + lane + 64] = a1;
}

__global__ __launch_bounds__(256)
void fused_edge_kernel(const float* __restrict__ feat,
                       const int* __restrict__ src, const int* __restrict__ dst,
                       const int* __restrict__ ety,
                       const float* __restrict__ weight,
                       float* __restrict__ out)
{
    const int wave  = threadIdx.x >> 6;
    const int lane  = threadIdx.x & 63;
    const int nwav  = gridDim.x * 4;
    for (int e = blockIdx.x * 4 + wave; e < NE; e += nwav) {
        const int s = src[e];
        const int d = dst[e];
        const int r = ety[e];
        const float2 fv = ((const float2*)(feat + (size_t)s * DD))[lane];
        const float* W = weight + (size_t)r * DD * DD;
        float a0 = 0.f, a1 = 0.f;
        for (int k = 0; k < 64; ++k) {
            float f0 = __shfl(fv.x, k, 64);
            float f1 = __shfl(fv.y, k, 64);
            a0 += f0 * W[(size_t)(2 * k) * DD + lane]
                + f1 * W[(size_t)(2 * k + 1) * DD + lane];
            a1 += f0 * W[(size_t)(2 * k) * DD + lane + 64]
                + f1 * W[(size_t)(2 * k + 1) * DD + lane + 64];
        }
        atomicAdd(out + (size_t)d * DD + lane,      SQ_A * a0);
        atomicAdd(out + (size_t)d * DD + lane + 64, SQ_A * a1);
    }
}

extern "C" void kernel_launch(void* const* d_in, const int* in_sizes, int n_in,
                              void* d_out, int out_size, void* d_ws, size_t ws_size,
                              hipStream_t stream)
{
    const float* feat   = (const float*)d_in[0];
    const int*   src    = (const int*)d_in[1];
    const int*   dst    = (const int*)d_in[2];
    const int*   ety    = (const int*)d_in[3];
    const float* weight = (const float*)d_in[4];
    const float* loop_w = (const float*)d_in[5];
    const float* h_bias = (const float*)d_in[6];
    float* out  = (float*)d_out;

    // Workspace layout (all sections 16B-multiple sized). ~15.3 MB total.
    char* p = (char*)d_ws;
    ushort* featb = (ushort*)p;  p += (size_t)NPAD * DD * 2;    // 12.81 MB
    ushort* wtb   = (ushort*)p;  p += (size_t)3 * DD * DD * 2;  // 96 KB
    int* offs     = (int*)p;     p += (size_t)OFFS_PAD * 4;
    int* cursor   = (int*)p;     p += (size_t)OFFS_PAD * 4;
    int* csum     = (int*)p;     p += 64 * 4;
    int* payload  = (int*)p;     p += (size_t)NE * 4;
    const size_t need_full = (size_t)(p - (char*)d_ws);

    if (ws_size >= need_full) {
        prep_kernel<<<(PREP_TASKS + 255) / 256, 256, 0, stream>>>(
            feat, weight, loop_w, featb, wtb, offs);
        hist_kernel<<<(NE + 255) / 256, 256, 0, stream>>>(dst, offs);
        scan_a_kernel<<<49, 1024, 0, stream>>>(offs, csum);
        scan_apply_kernel<<<49, 1024, 0, stream>>>(offs, cursor, csum);
        place_kernel<<<(NE + 255) / 256, 256, 0, stream>>>(
            src, dst, ety, cursor, payload);
        fused_agg_mfma_kernel<<<NTILE, 256, 0, stream>>>(
            featb, wtb, h_bias, offs, payload, out);
    } else {
        loop_init_kernel<<<(NN + 3) / 4, 256, 0, stream>>>(
            feat, loop_w, h_bias, out);
        fused_edge_kernel<<<dim3(2048), 256, 0, stream>>>(
            feat, src, dst, ety, weight, out);
    }
}

// Round 11
// 203.216 us; speedup vs baseline: 1.5677x; 1.1281x over previous
//
#include <hip/hip_runtime.h>

#define NN 50000
#define NPAD 50048           // 782 * 64 (featb rows, tail zeroed)
#define NE 500000
#define DD 128
#define NTILE 782            // ceil(NN/64)
#define OFFS_PAD 50176       // 49*1024, >= NN+1

// ALPHA = 0.5 → both sqrt(ALPHA) and sqrt(1-ALPHA) are sqrt(0.5).
__device__ __constant__ float SQ_A = 0.70710678118654752440f;

typedef __attribute__((ext_vector_type(8))) short short8;
typedef __attribute__((ext_vector_type(4))) float float4v;

// float → bf16 bits, round-to-nearest-even.
__device__ inline ushort f2bf(float f)
{
    uint u = __float_as_uint(f);
    u += 0x7fffu + ((u >> 16) & 1u);
    return (ushort)(u >> 16);
}
__device__ inline uint pk2(float a, float b)
{
    return (uint)f2bf(a) | ((uint)f2bf(b) << 16);
}
__device__ inline float bf_lo(uint d) { return __uint_as_float(d << 16); }
__device__ inline float bf_hi(uint d) { return __uint_as_float(d & 0xffff0000u); }

// ---------------------------------------------------------------------------
// Prep: feat fp32 → featb bf16 [NPAD][128] (rows >= NN zeroed);
//       W/loop_w → wtb bf16 [3][prow=128][k=128], scaled by sqrt(.5) and
//       ROW-PERMUTED so that B-frag row mq of tile nt holds actual column
//       col0 + 2*mq + nt → epilogue lanes own ADJACENT cols → packed stores.
//       prow(c) = (c>>5)*32 + (c&1)*16 + ((c&31)>>1).
//       zero offs[OFFS_PAD].
// ---------------------------------------------------------------------------
#define PREP_FEAT (NPAD * 16)        // 16 chunks of 8 elems per row
#define PREP_WTB  (3 * 2048)         // per seg: 16 k-chunks * 128 cols
#define PREP_ZERO (OFFS_PAD / 4)
#define PREP_TASKS (PREP_FEAT + PREP_WTB + PREP_ZERO)

__global__ __launch_bounds__(256)
void prep_kernel(const float* __restrict__ feat,
                 const float* __restrict__ weight,
                 const float* __restrict__ loop_w,
                 ushort* __restrict__ featb,
                 ushort* __restrict__ wtb,
                 int* __restrict__ offs)
{
    int t = blockIdx.x * 256 + threadIdx.x;
    if (t < PREP_FEAT) {
        int row = t >> 4;
        int c   = t & 15;            // k-chunk: elems c*8 .. c*8+7
        float4 v0 = make_float4(0.f, 0.f, 0.f, 0.f), v1 = v0;
        if (row < NN) {
            const float4* p = (const float4*)(feat + (size_t)row * DD + c * 8);
            v0 = p[0]; v1 = p[1];
        }
        uint4 pk;
        pk.x = pk2(v0.x, v0.y); pk.y = pk2(v0.z, v0.w);
        pk.z = pk2(v1.x, v1.y); pk.w = pk2(v1.z, v1.w);
        *(uint4*)&featb[(size_t)row * DD + c * 8] = pk;
    } else if (t < PREP_FEAT + PREP_WTB) {
        int u   = t - PREP_FEAT;
        int seg = u >> 11;           // 0,1 → relations; 2 → loop
        int c   = (u >> 7) & 15;     // k-chunk
        int col = u & 127;           // actual output column
        const float* wsrc = (seg < 2) ? (weight + (size_t)seg * DD * DD)
                                      : loop_w;
        float v[8];
#pragma unroll
        for (int j = 0; j < 8; ++j)
            v[j] = wsrc[(size_t)(c * 8 + j) * DD + col] * SQ_A;
        uint4 pk;
        pk.x = pk2(v[0], v[1]); pk.y = pk2(v[2], v[3]);
        pk.z = pk2(v[4], v[5]); pk.w = pk2(v[6], v[7]);
        int prow = (col >> 5) * 32 + ((col & 1) << 4) + ((col & 31) >> 1);
        *(uint4*)&wtb[((size_t)seg * DD + prow) * DD + c * 8] = pk;
    } else if (t < PREP_TASKS) {
        int u = t - (PREP_FEAT + PREP_WTB);
        ((int4*)offs)[u] = make_int4(0, 0, 0, 0);
    }
}

// ---------------------------------------------------------------------------
// Histogram.
// ---------------------------------------------------------------------------
__global__ __launch_bounds__(256)
void hist_kernel(const int* __restrict__ dst, int* __restrict__ offs)
{
    int e = blockIdx.x * 256 + threadIdx.x;
    if (e < NE) atomicAdd(&offs[dst[e]], 1);
}

// ---------------------------------------------------------------------------
// Parallel scan, two kernels over 49×1024 = OFFS_PAD elements (R8-proven).
// ---------------------------------------------------------------------------
__global__ __launch_bounds__(1024)
void scan_a_kernel(const int* __restrict__ offs, int* __restrict__ csum)
{
    __shared__ int ws[16];
    int i = blockIdx.x * 1024 + threadIdx.x;
    int v = offs[i];                       // padded region is zeroed
    for (int d = 32; d > 0; d >>= 1) v += __shfl_down(v, d, 64);
    int lane = threadIdx.x & 63, wv = threadIdx.x >> 6;
    if (lane == 0) ws[wv] = v;
    __syncthreads();
    if (threadIdx.x < 16) {
        int s = ws[threadIdx.x];
        for (int d = 8; d > 0; d >>= 1) s += __shfl_down(s, d, 64);
        if (threadIdx.x == 0) csum[blockIdx.x] = s;
    }
}

__global__ __launch_bounds__(1024)
void scan_apply_kernel(int* __restrict__ offs, int* __restrict__ cursor,
                       const int* __restrict__ csum)
{
    __shared__ int ws[16];
    const int bid  = blockIdx.x;
    const int lane = threadIdx.x & 63;
    const int wvi  = threadIdx.x >> 6;

    int base = 0;
    for (int b = 0; b < 49; ++b)
        if (b < bid) base += csum[b];

    int i = bid * 1024 + threadIdx.x;
    int v = offs[i];
    int inc = v;
#pragma unroll
    for (int d = 1; d < 64; d <<= 1) {
        int t = __shfl_up(inc, d, 64);
        if (lane >= d) inc += t;
    }
    if (lane == 63) ws[wvi] = inc;
    __syncthreads();
    int wbase = 0;
#pragma unroll
    for (int w = 0; w < 16; ++w) {
        int s = ws[w];
        if (w < wvi) wbase += s;
    }
    int excl = base + wbase + inc - v;
    offs[i] = excl;                        // i == NN gets total (=NE) ✓
    if (i < NN) cursor[i] = excl;
}

// payload[p] = (ety<<16) | src  (src < 65536 ✓).
__global__ __launch_bounds__(256)
void place_kernel(const int* __restrict__ src, const int* __restrict__ dst,
                  const int* __restrict__ ety,
                  int* __restrict__ cursor, int* __restrict__ payload)
{
    int e = blockIdx.x * 256 + threadIdx.x;
    if (e >= NE) return;
    int p = atomicAdd(&cursor[dst[e]], 1);
    payload[p] = (ety[e] << 16) | src[e];
}

// ---------------------------------------------------------------------------
// Fused aggregate + transform. One block per 64-node tile.
// Math: out[n] = bias + featb[n]@LWb + agg0[n]@W0b + agg1[n]@W1b
//   where agg_r[n] = Σ_{e: dst=n, ety=r} featb[src_e]  (fp32 acc → bf16).
// Phase 1 (gather): wave wv aggregates nodes [wv*16, wv*16+16); lane l owns
//   cols 2l,2l+1; 8 row-loads in flight (L3-latency bound otherwise).
// Phase 2 (MFMA): shared fp32 acc over 3 B-panels; afrag loads issued after
//   gather (frees VGPRs during gather; consumed in LAST panel for latency
//   hiding). Epilogue: 16 float2 stores (out).
// ---------------------------------------------------------------------------
__global__ __launch_bounds__(256, 4)
void fused_agg_mfma_kernel(const ushort* __restrict__ featb,
                           const ushort* __restrict__ wtb,
                           const float* __restrict__ h_bias,
                           const int* __restrict__ offs,
                           const int* __restrict__ payload,
                           float* __restrict__ out)
{
    __shared__ ushort sAgg[2][64][136];   // 34.8 KB

    const int tile  = blockIdx.x;
    const int node0 = tile * 64;
    const int wv    = threadIdx.x >> 6;
    const int lane  = threadIdx.x & 63;
    const int mq    = lane & 15;
    const int quad  = lane >> 4;
    const int col0  = wv * 32;

    // --- Phase 1: gather-aggregate 16 nodes per wave, 8 loads in flight. ---
#pragma unroll 1
    for (int i = 0; i < 16; ++i) {
        const int nl = wv * 16 + i;
        const int n  = node0 + nl;
        float2 s0[4], s1[4];
#pragma unroll
        for (int j = 0; j < 4; ++j) {
            s0[j] = make_float2(0.f, 0.f);
            s1[j] = make_float2(0.f, 0.f);
        }
        if (n < NN) {
            const int e0 = offs[n];
            const int e1 = offs[n + 1];
            int e = e0;
            for (; e + 8 <= e1; e += 8) {
                int p[8]; uint d[8];
#pragma unroll
                for (int j = 0; j < 8; ++j) p[j] = payload[e + j];
#pragma unroll
                for (int j = 0; j < 8; ++j)
                    d[j] = *(const uint*)&featb[(size_t)(p[j] & 0xffff) * DD + lane * 2];
#pragma unroll
                for (int j = 0; j < 8; ++j) {
                    float lx = bf_lo(d[j]), ly = bf_hi(d[j]);
                    bool r = (p[j] >> 16) != 0;
                    s0[j & 3].x += r ? 0.f : lx;  s0[j & 3].y += r ? 0.f : ly;
                    s1[j & 3].x += r ? lx : 0.f;  s1[j & 3].y += r ? ly : 0.f;
                }
            }
            if (e + 4 <= e1) {
                int p[4]; uint d[4];
#pragma unroll
                for (int j = 0; j < 4; ++j) p[j] = payload[e + j];
#pragma unroll
                for (int j = 0; j < 4; ++j)
                    d[j] = *(const uint*)&featb[(size_t)(p[j] & 0xffff) * DD + lane * 2];
#pragma unroll
                for (int j = 0; j < 4; ++j) {
                    float lx = bf_lo(d[j]), ly = bf_hi(d[j]);
                    bool r = (p[j] >> 16) != 0;
                    s0[j].x += r ? 0.f : lx;  s0[j].y += r ? 0.f : ly;
                    s1[j].x += r ? lx : 0.f;  s1[j].y += r ? ly : 0.f;
                }
                e += 4;
            }
            for (; e < e1; ++e) {
                int p0 = payload[e];
                uint d0 = *(const uint*)&featb[(size_t)(p0 & 0xffff) * DD + lane * 2];
                float lx = bf_lo(d0), ly = bf_hi(d0);
                bool r = (p0 >> 16) != 0;
                s0[0].x += r ? 0.f : lx;  s0[0].y += r ? 0.f : ly;
                s1[0].x += r ? lx : 0.f;  s1[0].y += r ? ly : 0.f;
            }
        }
        float ax = s0[0].x + s0[1].x + s0[2].x + s0[3].x;
        float ay = s0[0].y + s0[1].y + s0[2].y + s0[3].y;
        float bx = s1[0].x + s1[1].x + s1[2].x + s1[3].x;
        float by = s1[0].y + s1[1].y + s1[2].y + s1[3].y;
        *(uint*)&sAgg[0][nl][2 * lane] = pk2(ax, ay);
        *(uint*)&sAgg[1][nl][2 * lane] = pk2(bx, by);
    }

    // Issue featb A-frag loads now (consumed in the LAST panel).
    short8 afrag[4][4];
#pragma unroll
    for (int mt = 0; mt < 4; ++mt) {
        const ushort* arow = featb + (size_t)(node0 + mt * 16 + mq) * DD;
#pragma unroll
        for (int ks = 0; ks < 4; ++ks)
            afrag[mt][ks] = *(const short8*)&arow[ks * 32 + quad * 8];
    }
    __syncthreads();

    // --- Phase 2: MFMA, shared accumulator across 3 panels. ---
    float4v acc[4][2];
#pragma unroll
    for (int mt = 0; mt < 4; ++mt)
#pragma unroll
        for (int nt = 0; nt < 2; ++nt)
            acc[mt][nt] = (float4v){0.f, 0.f, 0.f, 0.f};

    // Panels: sAgg[r] @ W_r b (wtb segs 0,1) — LDS-sourced, afrag not needed.
#pragma unroll 1
    for (int r = 0; r < 2; ++r) {
        const ushort* wseg = wtb + (size_t)r * DD * DD;
        short8 bfrag[2][4];
#pragma unroll
        for (int nt = 0; nt < 2; ++nt)
#pragma unroll
            for (int ks = 0; ks < 4; ++ks)
                bfrag[nt][ks] = *(const short8*)
                    &wseg[(size_t)(col0 + nt * 16 + mq) * DD + ks * 32 + quad * 8];
#pragma unroll
        for (int mt = 0; mt < 4; ++mt)
#pragma unroll
            for (int ks = 0; ks < 4; ++ks) {
                short8 a = *(const short8*)&sAgg[r][mt * 16 + mq][ks * 32 + quad * 8];
#pragma unroll
                for (int nt = 0; nt < 2; ++nt)
                    acc[mt][nt] = __builtin_amdgcn_mfma_f32_16x16x32_bf16(
                        a, bfrag[nt][ks], acc[mt][nt], 0, 0, 0);
            }
    }

    // Panel: featb @ LWb (wtb seg 2) — afrag consumed last.
    {
        const ushort* wseg = wtb + (size_t)2 * DD * DD;
        short8 bfrag[2][4];
#pragma unroll
        for (int nt = 0; nt < 2; ++nt)
#pragma unroll
            for (int ks = 0; ks < 4; ++ks)
                bfrag[nt][ks] = *(const short8*)
                    &wseg[(size_t)(col0 + nt * 16 + mq) * DD + ks * 32 + quad * 8];
#pragma unroll
        for (int mt = 0; mt < 4; ++mt)
#pragma unroll
            for (int ks = 0; ks < 4; ++ks)
#pragma unroll
                for (int nt = 0; nt < 2; ++nt)
                    acc[mt][nt] = __builtin_amdgcn_mfma_f32_16x16x32_bf16(
                        afrag[mt][ks], bfrag[nt][ks], acc[mt][nt], 0, 0, 0);
    }

    // Epilogue. D row = quad*4 + rr; lane mq owns cols col0+2mq, +1.
    float2 bv = *(const float2*)&h_bias[col0 + 2 * mq];
#pragma unroll
    for (int mt = 0; mt < 4; ++mt) {
#pragma unroll
        for (int rr = 0; rr < 4; ++rr) {
            int node = node0 + mt * 16 + quad * 4 + rr;
            if (node < NN) {
                float2 v = make_float2(acc[mt][0][rr] + bv.x,
                                       acc[mt][1][rr] + bv.y);
                *(float2*)&out[(size_t)node * DD + col0 + 2 * mq] = v;
            }
        }
    }
}

// ---------------------------------------------------------------------------
// Fallback (small ws): fp32 out-init + fused per-edge matvec.
// ---------------------------------------------------------------------------
__global__ __launch_bounds__(256)
void loop_init_kernel(const float* __restrict__ feat,
                      const float* __restrict__ loop_weight,
                      const float* __restrict__ h_bias,
                      float* __restrict__ out)
{
    const int n = blockIdx.x * 4 + (threadIdx.x >> 6);
    if (n >= NN) return;
    const int lane = threadIdx.x & 63;
    const float2 fv = ((const float2*)(feat + (size_t)n * DD))[lane];
    float a0 = h_bias[lane], a1 = h_bias[lane + 64];
    for (int k = 0; k < 64; ++k) {
        float f0 = __shfl(fv.x, k, 64);
        float f1 = __shfl(fv.y, k, 64);
        a0 += SQ_A * (f0 * loop_weight[(size_t)(2 * k) * DD + lane]
                    + f1 * loop_weight[(size_t)(2 * k + 1) * DD + lane]);
        a1 += SQ_A * (f0 * loop_weight[(size_t)(2 * k) * DD + lane + 64]
                    + f1 * loop_weight[(size_t)(2 * k + 1) * DD + lane + 64]);
    }
    out[(size_t)n * DD + lane] = a0;
    out[(size_t)n * DD + lane + 64] = a1;
}

__global__ __launch_bounds__(256)
void fused_edge_kernel(const float* __restrict__ feat,
                       const int* __restrict__ src, const int* __restrict__ dst,
                       const int* __restrict__ ety,
                       const float* __restrict__ weight,
                       float* __restrict__ out)
{
    const int wave  = threadIdx.x >> 6;
    const int lane  = threadIdx.x & 63;
    const int nwav  = gridDim.x * 4;
    for (int e = blockIdx.x * 4 + wave; e < NE; e += nwav) {
        const int s = src[e];
        const int d = dst[e];
        const int r = ety[e];
        const float2 fv = ((const float2*)(feat + (size_t)s * DD))[lane];
        const float* W = weight + (size_t)r * DD * DD;
        float a0 = 0.f, a1 = 0.f;
        for (int k = 0; k < 64; ++k) {
            float f0 = __shfl(fv.x, k, 64);
            float f1 = __shfl(fv.y, k, 64);
            a0 += f0 * W[(size_t)(2 * k) * DD + lane]
                + f1 * W[(size_t)(2 * k + 1) * DD + lane];
            a1 += f0 * W[(size_t)(2 * k) * DD + lane + 64]
                + f1 * W[(size_t)(2 * k + 1) * DD + lane + 64];
        }
        atomicAdd(out + (size_t)d * DD + lane,      SQ_A * a0);
        atomicAdd(out + (size_t)d * DD + lane + 64, SQ_A * a1);
    }
}

extern "C" void kernel_launch(void* const* d_in, const int* in_sizes, int n_in,
                              void* d_out, int out_size, void* d_ws, size_t ws_size,
                              hipStream_t stream)
{
    const float* feat   = (const float*)d_in[0];
    const int*   src    = (const int*)d_in[1];
    const int*   dst    = (const int*)d_in[2];
    const int*   ety    = (const int*)d_in[3];
    const float* weight = (const float*)d_in[4];
    const float* loop_w = (const float*)d_in[5];
    const float* h_bias = (const float*)d_in[6];
    float* out  = (float*)d_out;

    // Workspace layout (all sections 16B-multiple sized). ~15.3 MB total.
    char* p = (char*)d_ws;
    ushort* featb = (ushort*)p;  p += (size_t)NPAD * DD * 2;    // 12.81 MB
    ushort* wtb   = (ushort*)p;  p += (size_t)3 * DD * DD * 2;  // 96 KB
    int* offs     = (int*)p;     p += (size_t)OFFS_PAD * 4;
    int* cursor   = (int*)p;     p += (size_t)OFFS_PAD * 4;
    int* csum     = (int*)p;     p += 64 * 4;
    int* payload  = (int*)p;     p += (size_t)NE * 4;
    const size_t need_full = (size_t)(p - (char*)d_ws);

    if (ws_size >= need_full) {
        prep_kernel<<<(PREP_TASKS + 255) / 256, 256, 0, stream>>>(
            feat, weight, loop_w, featb, wtb, offs);
        hist_kernel<<<(NE + 255) / 256, 256, 0, stream>>>(dst, offs);
        scan_a_kernel<<<49, 1024, 0, stream>>>(offs, csum);
        scan_apply_kernel<<<49, 1024, 0, stream>>>(offs, cursor, csum);
        place_kernel<<<(NE + 255) / 256, 256, 0, stream>>>(
            src, dst, ety, cursor, payload);
        fused_agg_mfma_kernel<<<NTILE, 256, 0, stream>>>(
            featb, wtb, h_bias, offs, payload, out);
    } else {
        loop_init_kernel<<<(NN + 3) / 4, 256, 0, stream>>>(
            feat, loop_w, h_bias, out);
        fused_edge_kernel<<<dim3(2048), 256, 0, stream>>>(
            feat, src, dst, ety, weight, out);
    }
}